// Round 6
// baseline (2015.921 us; speedup 1.0000x reference)
//
#include <hip/hip_runtime.h>
#include <cmath>

#define BLOCK 1024
#define NWAVE 16
#define NB 128
#define FINEB 4096
#define XLO -6.6f
#define CW 0.1f
#define ICW 10.0f

// inclusive scan across a 64-lane wave (lane order = index order)
__device__ __forceinline__ float wincl(float v, int lane) {
#pragma unroll
    for (int o = 1; o < 64; o <<= 1) {
        float x = __shfl_up(v, o, 64);
        if (lane >= o) v += x;
    }
    return v;
}

// Walk buckets in DESCENDING order; find first bucket where running inclusive
// mass (starting at base0) exceeds limit. One full wave executes.
__device__ __forceinline__ void find_crit_desc(const float* h, int n, int seg,
                                               float base0, float limit, int lane,
                                               int* out_b, float* out_A) {
    float segsum = 0.f;
    int start = n - 1 - lane * seg;
    for (int k = 0; k < seg; k++) segsum += h[start - k];
    float incl = wincl(segsum, lane);
    unsigned long long mk = __ballot(base0 + incl > limit);
    if (mk == 0ULL) { *out_b = 0; *out_A = base0; return; }
    int fl = __ffsll(mk) - 1;
    float base = base0 + __shfl(incl, fl, 64) - __shfl(segsum, fl, 64);
    int sstart = n - 1 - fl * seg;
    float v = (lane < seg) ? h[sstart - lane] : 0.f;
    float incl2 = wincl(v, lane);
    unsigned long long mk2 = __ballot((lane < seg) && (base + incl2 > limit));
    int k2 = mk2 ? (__ffsll(mk2) - 1) : (seg - 1);
    *out_b = sstart - k2;
    *out_A = base + __shfl(incl2, k2, 64) - __shfl(v, k2, 64);
}

// monotone (total-order) key of a float's bit pattern
__device__ __forceinline__ unsigned okey(unsigned bits) {
    return (bits & 0x80000000u) ? ~bits : (bits | 0x80000000u);
}

// ---------------------------------------------------------------------------
// K1: partial Z + exactly-1/8 subsampled coarse histogram (128 bins)
// ---------------------------------------------------------------------------
__global__ __launch_bounds__(BLOCK) void ns_k1(const float* __restrict__ logits,
        const int* __restrict__ temp, float* __restrict__ Z,
        unsigned* __restrict__ CH, int V) {
    const int row = blockIdx.x >> 2, part = blockIdx.x & 3;
    const float* __restrict__ row_p = logits + (size_t)row * (size_t)V;
    const int t = threadIdx.x, lane = t & 63, wave = t >> 6;
    __shared__ unsigned lh[NB];
    __shared__ float sweep[NWAVE];
    const float invt = 1.0f / (float)temp[0];
    const float REF = (XLO + NB * CW) * invt;
    if (t < NB) lh[t] = 0u;
    __syncthreads();
    const int q4 = (V >> 2) & ~3;        // per-part span, multiple of 4 (and 8)
    const int lo = q4 * part;
    const int hi = (part == 3) ? V : lo + q4;
    const int S = BLOCK * 4;
    float zp = 0.f;
#define EXPR(x) __expf(fmaf((x), invt, -REF))
#define SAMP(x, e) { int bb = (int)(((x) - XLO) * ICW); bb = max(0, min(NB - 1, bb)); \
                     atomicAdd(&lh[bb], (unsigned)((e) * 4194304.f + 0.5f)); }
    int i = lo + t * 4;
    for (; i + 3 * S + 3 < hi; i += 4 * S) {
        float4 a = *(const float4*)(row_p + i);
        float4 b = *(const float4*)(row_p + i + S);
        float4 c = *(const float4*)(row_p + i + 2 * S);
        float4 d = *(const float4*)(row_p + i + 3 * S);
        float e0 = EXPR(a.x), e1 = EXPR(a.y), e2 = EXPR(a.z), e3 = EXPR(a.w);
        float f0 = EXPR(b.x), f1 = EXPR(b.y), f2 = EXPR(b.z), f3 = EXPR(b.w);
        float g0 = EXPR(c.x), g1 = EXPR(c.y), g2 = EXPR(c.z), g3 = EXPR(c.w);
        float h0 = EXPR(d.x), h1 = EXPR(d.y), h2 = EXPR(d.z), h3 = EXPR(d.w);
        zp += ((e0 + e1) + (e2 + e3)) + ((f0 + f1) + (f2 + f3))
            + ((g0 + g1) + (g2 + g3)) + ((h0 + h1) + (h2 + h3));
        // sample element iff global index % 8 == 0  (base addresses share i&4)
        if ((i & 4) == 0) { SAMP(a.x, e0); SAMP(b.x, f0); SAMP(c.x, g0); SAMP(d.x, h0); }
    }
    for (; i + 3 < hi; i += S) {
        float4 a = *(const float4*)(row_p + i);
        float e0 = EXPR(a.x), e1 = EXPR(a.y), e2 = EXPR(a.z), e3 = EXPR(a.w);
        zp += (e0 + e1) + (e2 + e3);
        if ((i & 4) == 0) SAMP(a.x, e0);
    }
    {
        int ts = hi & ~3;
        for (int j = ts + t; j < hi; j += BLOCK) {
            float x = row_p[j];
            float e = EXPR(x);
            zp += e;
            if ((j & 7) == 0) SAMP(x, e);
        }
    }
#pragma unroll
    for (int o = 32; o >= 1; o >>= 1) zp += __shfl_xor(zp, o, 64);
    if (lane == 0) sweep[wave] = zp;
    __syncthreads();
    if (t == 0) {
        float z = 0.f;
        for (int w = 0; w < NWAVE; w++) z += sweep[w];
        atomicAdd(&Z[row], z);
    }
    if (t < NB && lh[t]) atomicAdd(&CH[row * NB + t], lh[t]);
#undef SAMP
}

// ---------------------------------------------------------------------------
// K2: band from coarse walk; chunk sums + above-band mass + band compaction
//     (global list) + fine 4096-bin histogram (global atomics)
// ---------------------------------------------------------------------------
__global__ __launch_bounds__(BLOCK) void ns_k2(const float* __restrict__ logits,
        const int* __restrict__ temp, const float* __restrict__ Z,
        const unsigned* __restrict__ CH, float* __restrict__ SA,
        unsigned* __restrict__ CNT, float* __restrict__ CS,
        unsigned* __restrict__ FH, unsigned* __restrict__ LIST,
        int V, int listcap) {
    const int row = blockIdx.x >> 2, part = blockIdx.x & 3;
    const float* __restrict__ row_p = logits + (size_t)row * (size_t)V;
    const int t = threadIdx.x, lane = t & 63, wave = t >> 6;
    __shared__ float chf[NB];
    __shared__ float sweep[NWAVE];
    __shared__ int bandi[1];
    const float invt = 1.0f / (float)temp[0];
    const float REF = (XLO + NB * CW) * invt;
    if (t < NB) chf[t] = (float)CH[row * NB + t] * (8.f / 4194304.f);
    __syncthreads();
    const float limit = 0.9f * Z[row];
    if (wave == 0) {
        int c0; float A0;
        find_crit_desc(chf, NB, 2, 0.f, limit, lane, &c0, &A0);
        if (lane == 0) bandi[0] = c0;
    }
    __syncthreads();
    const int c0 = bandi[0];
    const int blo_b = max(0, c0 - 2), bhi_b = min(NB - 1, c0 + 2);
    const float blo = XLO + (float)blo_b * CW;
    const float bandW = (float)(bhi_b - blo_b + 1) * CW;
    const float bhi = blo + bandW;
    const float binS = (float)FINEB / bandW;
    unsigned* FHrow = FH + (size_t)row * FINEB;
    unsigned* LROW = LIST + (size_t)row * (size_t)listcap;
    const int nch = (V + 1023) >> 10;
    const int cper = (nch + 3) >> 2;
    const int cstart = part * cper;
    const int cend = min(nch, cstart + cper);
    float sa = 0.f;
#define PROC2(xx, kk) { \
        int bb = (int)(((xx) - XLO) * ICW); bb = max(0, min(NB - 1, bb)); \
        float e = __expf(fmaf((xx), invt, -REF)); \
        if (bb >= blo_b) s += e; \
        if (bb > bhi_b) sa += e; \
        bool inb = (bb >= blo_b) && (bb <= bhi_b) && ((i0 + (kk)) < V); \
        unsigned long long mask = __ballot(inb); \
        if (mask) { if (inb) { \
            int bpos = 0; int leader = __ffsll(mask) - 1; \
            if (lane == leader) bpos = (int)atomicAdd(&CNT[row], (unsigned)__popcll(mask)); \
            bpos = __builtin_amdgcn_readfirstlane(bpos); \
            int pos = bpos + (int)__popcll(mask & ((1ull << lane) - 1ull)); \
            if (pos < listcap) LROW[pos] = (unsigned)(i0 + (kk)); \
            int bin = (int)(((xx) - blo) * binS); bin = max(0, min(FINEB - 1, bin)); \
            atomicAdd(&FHrow[bin], \
                      (unsigned)(__expf(((xx) - bhi) * invt) * 16777216.f + 0.5f)); \
        } } }
    for (int c = cstart + wave; c < cend; c += NWAVE) {
        float s = 0.f;
        const int base = c << 10;
#pragma unroll
        for (int q = 0; q < 4; q++) {
            int i0 = base + q * 256 + lane * 4;
            float x0, x1, x2, x3;
            if (i0 + 3 < V) {
                float4 v = *(const float4*)(row_p + i0);
                x0 = v.x; x1 = v.y; x2 = v.z; x3 = v.w;
            } else {
                x0 = (i0 < V) ? row_p[i0] : -1e30f;
                x1 = (i0 + 1 < V) ? row_p[i0 + 1] : -1e30f;
                x2 = (i0 + 2 < V) ? row_p[i0 + 2] : -1e30f;
                x3 = (i0 + 3 < V) ? row_p[i0 + 3] : -1e30f;
            }
            PROC2(x0, 0) PROC2(x1, 1) PROC2(x2, 2) PROC2(x3, 3)
        }
#pragma unroll
        for (int o = 32; o >= 1; o >>= 1) s += __shfl_xor(s, o, 64);
        if (lane == 0) CS[row * 128 + c] = s;
    }
#pragma unroll
    for (int o = 32; o >= 1; o >>= 1) sa += __shfl_xor(sa, o, 64);
    if (lane == 0) sweep[wave] = sa;
    __syncthreads();
    if (t == 0) {
        float s2 = 0.f;
        for (int w = 0; w < NWAVE; w++) s2 += sweep[w];
        atomicAdd(&SA[row], s2);
    }
#undef PROC2
}

// ---------------------------------------------------------------------------
// K3: fine walk -> exact threshold; corrections from list; token selection
// ---------------------------------------------------------------------------
__global__ __launch_bounds__(BLOCK) void ns_k3(const float* __restrict__ logits,
        const float* __restrict__ uvec, const int* __restrict__ temp,
        const float* __restrict__ Z, const unsigned* __restrict__ CH,
        const float* __restrict__ SA, const unsigned* __restrict__ CNT,
        const float* __restrict__ CS, const unsigned* __restrict__ FH,
        const unsigned* __restrict__ LIST, int* __restrict__ out,
        int V, int listcap) {
    const int row = blockIdx.x;
    const float* __restrict__ row_p = logits + (size_t)row * (size_t)V;
    const int t = threadIdx.x, lane = t & 63, wave = t >> 6;
    __shared__ float fhf[FINEB];
    __shared__ unsigned cs_u[128];
    __shared__ int bandi[1];
    __shared__ unsigned tk_s[1];
    const float invt = 1.0f / (float)temp[0];
    const float REF = (XLO + NB * CW) * invt;

    // coarse walk: must match K2 bit-exactly
    if (t < NB) fhf[t] = (float)CH[row * NB + t] * (8.f / 4194304.f);
    __syncthreads();
    const float limit = 0.9f * Z[row];
    if (wave == 0) {
        int c0; float A0;
        find_crit_desc(fhf, NB, 2, 0.f, limit, lane, &c0, &A0);
        if (lane == 0) bandi[0] = c0;
    }
    __syncthreads();
    const int c0 = bandi[0];
    const int blo_b = max(0, c0 - 2), bhi_b = min(NB - 1, c0 + 2);
    const float blo = XLO + (float)blo_b * CW;
    const float bandW = (float)(bhi_b - blo_b + 1) * CW;
    const float bhi = blo + bandW;

    // fine hist -> float masses in LDS; csum -> fixed point 2^20
    const float CFc = __expf(fmaf(bhi, invt, -REF)) * (1.f / 16777216.f);
    for (int i = t; i < FINEB; i += BLOCK)
        fhf[i] = (float)FH[(size_t)row * FINEB + i] * CFc;
    if (t < 128) cs_u[t] = (unsigned)(CS[row * 128 + t] * 1048576.f + 0.5f);
    __syncthreads();

    const float Sa = SA[row];
    if (wave == 0) {
        int f0; float A2;
        find_crit_desc(fhf, FINEB, 64, Sa, limit, lane, &f0, &A2);
        if (lane == 0) {
            float Tx = blo + (float)f0 * (bandW * (1.f / (float)FINEB));
            tk_s[0] = okey(__float_as_uint(Tx));
        }
    }
    __syncthreads();
    const unsigned Tk = tk_s[0];   // keep <=> okey(bits(x)) >= Tk

    // corrections: remove below-threshold band mass from chunk sums
    {
        int n = (int)CNT[row];
        if (n > listcap) n = listcap;
        const unsigned* LROW = LIST + (size_t)row * (size_t)listcap;
        for (int p = t; p < n; p += BLOCK) {
            unsigned ii = LROW[p];
            float x = row_p[ii];
            if (okey(__float_as_uint(x)) < Tk) {
                float e = __expf(fmaf(x, invt, -REF));
                atomicAdd(&cs_u[ii >> 10], (unsigned)(-(int)(e * 1048576.f + 0.5f)));
            }
        }
    }
    __syncthreads();

    // final: locate token in the crossing chunk
    if (wave == 0) {
        auto rd = [&](int j) -> float {
            int v = (int)cs_u[j];
            return v > 0 ? (float)v * (1.f / 1048576.f) : 0.f;
        };
        float segsum = rd(lane * 2) + rd(lane * 2 + 1);
        float incl = wincl(segsum, lane);
        float total = __shfl(incl, 63, 64);            // Z_kept
        const float U = uvec[row] * total;
        unsigned long long mk = __ballot(incl >= U);
        int token;
        if (mk == 0ULL) {
            token = V;
        } else {
            int fl = __ffsll(mk) - 1;
            float base = __shfl(incl, fl, 64) - __shfl(segsum, fl, 64);
            float v = (lane < 2) ? rd(fl * 2 + lane) : 0.f;
            float incl2 = wincl(v, lane);
            unsigned long long mk2 = __ballot((lane < 2) && (base + incl2 >= U));
            int k2 = mk2 ? (__ffsll(mk2) - 1) : 1;
            int cx = fl * 2 + k2;                      // crossing chunk
            float Bm = base + __shfl(incl2, k2, 64) - __shfl(v, k2, 64);
            int cb = cx << 10;
            float vv[16];
#pragma unroll
            for (int r = 0; r < 16; r++) {
                int idx = cb + r * 64 + lane;
                vv[r] = (idx < V) ? row_p[idx] : -1e30f;
            }
            int cnt2 = 0;
#pragma unroll
            for (int r = 0; r < 16; r++) {
                int idx = cb + r * 64 + lane;
                unsigned kk = okey(__float_as_uint(vv[r]));
                float e = __expf(fmaf(vv[r], invt, -REF));
                float keep = (kk >= Tk) ? e : 0.f;
                float is = wincl(keep, lane);
                unsigned long long mm = __ballot((idx < V) && (Bm + is < U));
                cnt2 += __popcll(mm);
                Bm += __shfl(is, 63, 64);
            }
            token = cb + cnt2;
        }
        if (lane == 0) out[row] = (token < V - 1) ? token : (V - 1);
    }
}

extern "C" void kernel_launch(void* const* d_in, const int* in_sizes, int n_in,
                              void* d_out, int out_size, void* d_ws, size_t ws_size,
                              hipStream_t stream) {
    const float* logits = (const float*)d_in[0];
    const float* u = (const float*)d_in[1];
    const int* temp = (const int*)d_in[2];
    int* out = (int*)d_out;
    int B = in_sizes[1];
    int V = in_sizes[0] / B;

    char* ws = (char*)d_ws;
    size_t off = 0;
    float* Z = (float*)(ws + off);      off += (size_t)B * 4;
    float* SA = (float*)(ws + off);     off += (size_t)B * 4;
    unsigned* CNT = (unsigned*)(ws + off); off += (size_t)B * 4;
    unsigned* CH = (unsigned*)(ws + off);  off += (size_t)B * NB * 4;
    float* CS = (float*)(ws + off);     off += (size_t)B * 128 * 4;
    unsigned* FH = (unsigned*)(ws + off);  off += (size_t)B * FINEB * 4;
    size_t zero_bytes = off;
    unsigned* LIST = (unsigned*)(ws + off);
    size_t rem = (ws_size > off) ? (ws_size - off) : 0;
    size_t cap = rem / ((size_t)B * 4);
    int listcap = (cap > 32768) ? 32768 : (int)cap;
    if (listcap < 64) listcap = 64;

    hipMemsetAsync(d_ws, 0, zero_bytes, stream);
    ns_k1<<<B * 4, BLOCK, 0, stream>>>(logits, temp, Z, CH, V);
    ns_k2<<<B * 4, BLOCK, 0, stream>>>(logits, temp, Z, CH, SA, CNT, CS, FH, LIST, V, listcap);
    ns_k3<<<B, BLOCK, 0, stream>>>(logits, u, temp, Z, CH, SA, CNT, CS, FH, LIST, out, V, listcap);
}

// Round 7
// 271.313 us; speedup vs baseline: 7.4302x; 7.4302x over previous
//
#include <hip/hip_runtime.h>
#include <cmath>

#define NB 128
#define FINEB 4096
#define XLO -6.6f
#define CW 0.1f
#define ICW 10.0f
#define XHIB 6.2f          // XLO + NB*CW

// inclusive scan across a 64-lane wave (lane order = index order)
__device__ __forceinline__ float wincl(float v, int lane) {
#pragma unroll
    for (int o = 1; o < 64; o <<= 1) {
        float x = __shfl_up(v, o, 64);
        if (lane >= o) v += x;
    }
    return v;
}

// Walk buckets in DESCENDING order; find first bucket where running inclusive
// mass (starting at base0) exceeds limit. One full wave executes.
__device__ __forceinline__ void find_crit_desc(const float* h, int n, int seg,
                                               float base0, float limit, int lane,
                                               int* out_b, float* out_A) {
    float segsum = 0.f;
    int start = n - 1 - lane * seg;
    for (int k = 0; k < seg; k++) segsum += h[start - k];
    float incl = wincl(segsum, lane);
    unsigned long long mk = __ballot(base0 + incl > limit);
    if (mk == 0ULL) { *out_b = 0; *out_A = base0; return; }
    int fl = __ffsll(mk) - 1;
    float base = base0 + __shfl(incl, fl, 64) - __shfl(segsum, fl, 64);
    int sstart = n - 1 - fl * seg;
    float v = (lane < seg) ? h[sstart - lane] : 0.f;
    float incl2 = wincl(v, lane);
    unsigned long long mk2 = __ballot((lane < seg) && (base + incl2 > limit));
    int k2 = mk2 ? (__ffsll(mk2) - 1) : (seg - 1);
    *out_b = sstart - k2;
    *out_A = base + __shfl(incl2, k2, 64) - __shfl(v, k2, 64);
}

// monotone (total-order) key of a float's bit pattern
__device__ __forceinline__ unsigned okey(unsigned bits) {
    return (bits & 0x80000000u) ? ~bits : (bits | 0x80000000u);
}

// ---------------------------------------------------------------------------
// A: partial Z (exact) + 1/8-sampled coarse hist per (row, part). grid=B*8.
// ---------------------------------------------------------------------------
__global__ __launch_bounds__(256, 8) void ns_a(const float* __restrict__ logits,
        const int* __restrict__ temp, float* __restrict__ Zp,
        unsigned* __restrict__ CHp, int V) {
    const int row = blockIdx.x >> 3, part = blockIdx.x & 7;
    const float* __restrict__ row_p = logits + (size_t)row * (size_t)V;
    const int t = threadIdx.x, lane = t & 63, wave = t >> 6;
    __shared__ unsigned lh[NB];
    __shared__ float sw[4];
    const float invt = 1.0f / (float)temp[0];
    const float REF = XHIB * invt;
    if (t < NB) lh[t] = 0u;
    __syncthreads();
    float zp = 0.f;
    const bool samp = ((t & 1) == 0);
    int i = (part * 256 + t) * 4;
    for (; i + 3 < V; i += 8192) {
        float4 v = *(const float4*)(row_p + i);
        float e0 = __expf(fmaf(v.x, invt, -REF));
        float e1 = __expf(fmaf(v.y, invt, -REF));
        float e2 = __expf(fmaf(v.z, invt, -REF));
        float e3 = __expf(fmaf(v.w, invt, -REF));
        zp += (e0 + e1) + (e2 + e3);
        if (samp) {   // element index i: i%8==0 exactly when (part*256+t) even
            int bb = (int)((v.x - XLO) * ICW);
            bb = max(0, min(NB - 1, bb));
            atomicAdd(&lh[bb], (unsigned)(e0 * 4194304.f + 0.5f));  // 2^22
        }
    }
    if (part == 0) {   // scalar tail
        int V4 = V & ~3;
        for (int j = V4 + t; j < V; j += 256) {
            float x = row_p[j];
            float e = __expf(fmaf(x, invt, -REF));
            zp += e;
            if ((j & 7) == 0) {
                int bb = (int)((x - XLO) * ICW);
                bb = max(0, min(NB - 1, bb));
                atomicAdd(&lh[bb], (unsigned)(e * 4194304.f + 0.5f));
            }
        }
    }
#pragma unroll
    for (int o = 32; o >= 1; o >>= 1) zp += __shfl_xor(zp, o, 64);
    if (lane == 0) sw[wave] = zp;
    __syncthreads();
    if (t == 0) Zp[row * 8 + part] = sw[0] + sw[1] + sw[2] + sw[3];
    if (t < NB) CHp[(size_t)(row * 8 + part) * NB + t] = lh[t];
}

// ---------------------------------------------------------------------------
// A2: merge part hists; coarse walk -> c0, limit. grid=B, block=128.
// ---------------------------------------------------------------------------
__global__ __launch_bounds__(128) void ns_a2(const float* __restrict__ Zp,
        const unsigned* __restrict__ CHp, float* __restrict__ LIM,
        int* __restrict__ C0) {
    const int row = blockIdx.x;
    const int t = threadIdx.x, lane = t & 63, wave = t >> 6;
    __shared__ float chf[NB];
    __shared__ float limS[1];
    if (t < NB) {
        unsigned s = 0;
        for (int p = 0; p < 8; p++) s += CHp[(size_t)(row * 8 + p) * NB + t];
        chf[t] = (float)s * (8.f / 4194304.f);
    }
    if (t == 0) {
        float z = 0.f;
        for (int p = 0; p < 8; p++) z += Zp[row * 8 + p];
        float lim = 0.9f * z;
        limS[0] = lim;
        LIM[row] = lim;
    }
    __syncthreads();
    if (wave == 0) {
        int c0; float A0;
        find_crit_desc(chf, NB, 2, 0.f, limS[0], lane, &c0, &A0);
        if (lane == 0) C0[row] = c0;
    }
}

// ---------------------------------------------------------------------------
// B: chunk kept-sums (exact) + above-band mass + band compaction. grid=B*8.
// ---------------------------------------------------------------------------
__global__ __launch_bounds__(256, 8) void ns_b(const float* __restrict__ logits,
        const int* __restrict__ temp, const int* __restrict__ C0,
        float* __restrict__ SAp, float* __restrict__ CS,
        unsigned* __restrict__ CNTp, unsigned* __restrict__ LISTV,
        unsigned* __restrict__ LISTI, int V, int cap8) {
    const int row = blockIdx.x >> 3, part = blockIdx.x & 7;
    const float* __restrict__ row_p = logits + (size_t)row * (size_t)V;
    const int t = threadIdx.x, lane = t & 63, wave = t >> 6;
    __shared__ float sw[4];
    __shared__ int lcnt;
    const float invt = 1.0f / (float)temp[0];
    const float REF = XHIB * invt;
    if (t == 0) lcnt = 0;
    __syncthreads();
    const int c0 = C0[row];
    const int blo_b = max(0, c0 - 2), bhi_b = min(NB - 1, c0 + 2);
    const int nch = (V + 1023) >> 10;
    const int cper = (nch + 7) >> 3;
    const int cst = part * cper;
    const int cen = min(nch, cst + cper);
    unsigned* LV = LISTV + (size_t)(row * 8 + part) * (size_t)cap8;
    unsigned* LI = LISTI + (size_t)(row * 8 + part) * (size_t)cap8;
    float sa = 0.f;
#define PROCB(xx, ii) { \
        float e = __expf(fmaf((xx), invt, -REF)); \
        int bb = (int)(((xx) - XLO) * ICW); bb = max(0, min(NB - 1, bb)); \
        if (bb >= blo_b) s += e; \
        if (bb > bhi_b) sa += e; \
        bool inb = (bb >= blo_b) && (bb <= bhi_b) && ((ii) < V); \
        unsigned long long mask = __ballot(inb); \
        if (inb) { \
            int pos0 = 0; int leader = __ffsll(mask) - 1; \
            if (lane == leader) pos0 = atomicAdd(&lcnt, (int)__popcll(mask)); \
            pos0 = __builtin_amdgcn_readfirstlane(pos0); \
            int pos = pos0 + (int)__popcll(mask & ((1ull << lane) - 1ull)); \
            if (pos < cap8) { LV[pos] = __float_as_uint(xx); LI[pos] = (unsigned)(ii); } \
        } }
    for (int c = cst + wave; c < cen; c += 4) {
        float s = 0.f;
        const int base = c << 10;
#pragma unroll
        for (int q = 0; q < 4; q++) {
            int i0 = base + q * 256 + lane * 4;
            float x0, x1, x2, x3;
            if (i0 + 3 < V) {
                float4 v = *(const float4*)(row_p + i0);
                x0 = v.x; x1 = v.y; x2 = v.z; x3 = v.w;
            } else {
                x0 = (i0 < V) ? row_p[i0] : -1e30f;
                x1 = (i0 + 1 < V) ? row_p[i0 + 1] : -1e30f;
                x2 = (i0 + 2 < V) ? row_p[i0 + 2] : -1e30f;
                x3 = (i0 + 3 < V) ? row_p[i0 + 3] : -1e30f;
            }
            PROCB(x0, i0) PROCB(x1, i0 + 1) PROCB(x2, i0 + 2) PROCB(x3, i0 + 3)
        }
#pragma unroll
        for (int o = 32; o >= 1; o >>= 1) s += __shfl_xor(s, o, 64);
        if (lane == 0) CS[row * 128 + c] = s;
    }
#pragma unroll
    for (int o = 32; o >= 1; o >>= 1) sa += __shfl_xor(sa, o, 64);
    if (lane == 0) sw[wave] = sa;
    __syncthreads();
    if (t == 0) {
        SAp[row * 8 + part] = sw[0] + sw[1] + sw[2] + sw[3];
        CNTp[row * 8 + part] = (unsigned)min(lcnt, cap8);
    }
#undef PROCB
}

// ---------------------------------------------------------------------------
// C: fine hist from list; walk -> threshold; corrections; token. grid=B.
// ---------------------------------------------------------------------------
__global__ __launch_bounds__(1024) void ns_c(const float* __restrict__ logits,
        const float* __restrict__ uvec, const int* __restrict__ temp,
        const float* __restrict__ LIM, const int* __restrict__ C0,
        const float* __restrict__ SAp, const float* __restrict__ CS,
        const unsigned* __restrict__ CNTp, const unsigned* __restrict__ LISTV,
        const unsigned* __restrict__ LISTI, int* __restrict__ out,
        int V, int cap8) {
    const int row = blockIdx.x;
    const float* __restrict__ row_p = logits + (size_t)row * (size_t)V;
    const int t = threadIdx.x, lane = t & 63, wave = t >> 6;
    __shared__ float fhf[FINEB];          // u32 during build, float after
    __shared__ unsigned cs_u[128];
    __shared__ float shSa[1];
    __shared__ unsigned tk_s[1];
    const float invt = 1.0f / (float)temp[0];
    const float REF = XHIB * invt;
    const float limit = LIM[row];
    const int c0 = C0[row];
    const int blo_b = max(0, c0 - 2), bhi_b = min(NB - 1, c0 + 2);
    const float blo = XLO + (float)blo_b * CW;
    const float bandW = (float)(bhi_b - blo_b + 1) * CW;
    const float bhi = blo + bandW;
    const float binS = (float)FINEB / bandW;
    const int nch = (V + 1023) >> 10;
    unsigned* fhu = (unsigned*)fhf;

    for (int i = t; i < FINEB; i += 1024) fhu[i] = 0u;
    if (t < 128) cs_u[t] = (t < nch) ? (unsigned)(CS[row * 128 + t] * 1048576.f + 0.5f) : 0u;
    if (t == 0) {
        float s = 0.f;
        for (int p = 0; p < 8; p++) s += SAp[row * 8 + p];
        shSa[0] = s;
    }
    __syncthreads();

    // fine hist from compacted band values (scale 2^16, relative to bhi)
    for (int p = 0; p < 8; p++) {
        int n = (int)CNTp[row * 8 + p];
        const unsigned* LV = LISTV + (size_t)(row * 8 + p) * (size_t)cap8;
        for (int j = t; j < n; j += 1024) {
            float x = __uint_as_float(LV[j]);
            int bin = (int)((x - blo) * binS);
            bin = max(0, min(FINEB - 1, bin));
            float er = __expf((x - bhi) * invt);
            atomicAdd(&fhu[bin], (unsigned)(er * 65536.f + 0.5f));
        }
    }
    __syncthreads();
    const float CFc = __expf(fmaf(bhi, invt, -REF)) * (1.f / 65536.f);
    for (int i = t; i < FINEB; i += 1024) {
        unsigned c = fhu[i];
        fhf[i] = (float)c * CFc;
    }
    __syncthreads();
    if (wave == 0) {
        int f0; float A2;
        find_crit_desc(fhf, FINEB, 64, shSa[0], limit, lane, &f0, &A2);
        if (lane == 0) {
            float Tx = blo + (float)f0 * (bandW * (1.f / (float)FINEB));
            tk_s[0] = okey(__float_as_uint(Tx));
        }
    }
    __syncthreads();
    const unsigned Tk = tk_s[0];   // keep <=> okey(bits(x)) >= Tk

    // corrections: subtract below-threshold band mass from its chunk sum
    for (int p = 0; p < 8; p++) {
        int n = (int)CNTp[row * 8 + p];
        const unsigned* LV = LISTV + (size_t)(row * 8 + p) * (size_t)cap8;
        const unsigned* LI = LISTI + (size_t)(row * 8 + p) * (size_t)cap8;
        for (int j = t; j < n; j += 1024) {
            float x = __uint_as_float(LV[j]);
            if (okey(__float_as_uint(x)) < Tk) {
                float e = __expf(fmaf(x, invt, -REF));
                unsigned ii = LI[j];
                atomicAdd(&cs_u[ii >> 10], (unsigned)(-(int)(e * 1048576.f + 0.5f)));
            }
        }
    }
    __syncthreads();

    // final: locate token in the crossing chunk
    if (wave == 0) {
        auto rd = [&](int j) -> float {
            int v = (int)cs_u[j];
            return v > 0 ? (float)v * (1.f / 1048576.f) : 0.f;
        };
        float segsum = rd(lane * 2) + rd(lane * 2 + 1);
        float incl = wincl(segsum, lane);
        float total = __shfl(incl, 63, 64);            // Z_kept
        const float U = uvec[row] * total;
        unsigned long long mk = __ballot(incl >= U);
        int token;
        if (mk == 0ULL) {
            token = V;
        } else {
            int fl = __ffsll(mk) - 1;
            float base = __shfl(incl, fl, 64) - __shfl(segsum, fl, 64);
            float v = (lane < 2) ? rd(fl * 2 + lane) : 0.f;
            float incl2 = wincl(v, lane);
            unsigned long long mk2 = __ballot((lane < 2) && (base + incl2 >= U));
            int k2 = mk2 ? (__ffsll(mk2) - 1) : 1;
            int cx = fl * 2 + k2;                      // crossing chunk
            float Bm = base + __shfl(incl2, k2, 64) - __shfl(v, k2, 64);
            int cb = cx << 10;
            float vv[16];
#pragma unroll
            for (int r = 0; r < 16; r++) {
                int idx = cb + r * 64 + lane;
                vv[r] = (idx < V) ? row_p[idx] : -1e30f;
            }
            int cnt2 = 0;
#pragma unroll
            for (int r = 0; r < 16; r++) {
                int idx = cb + r * 64 + lane;
                unsigned kk = okey(__float_as_uint(vv[r]));
                float e = __expf(fmaf(vv[r], invt, -REF));
                float keep = (kk >= Tk) ? e : 0.f;
                float is = wincl(keep, lane);
                unsigned long long mm = __ballot((idx < V) && (Bm + is < U));
                cnt2 += __popcll(mm);
                Bm += __shfl(is, 63, 64);
            }
            token = cb + cnt2;
        }
        if (lane == 0) out[row] = (token < V - 1) ? token : (V - 1);
    }
}

extern "C" void kernel_launch(void* const* d_in, const int* in_sizes, int n_in,
                              void* d_out, int out_size, void* d_ws, size_t ws_size,
                              hipStream_t stream) {
    const float* logits = (const float*)d_in[0];
    const float* u = (const float*)d_in[1];
    const int* temp = (const int*)d_in[2];
    int* out = (int*)d_out;
    int B = in_sizes[1];
    int V = in_sizes[0] / B;

    char* ws = (char*)d_ws;
    size_t off = 0;
    float* Zp = (float*)(ws + off);       off += (size_t)B * 8 * 4;
    float* SAp = (float*)(ws + off);      off += (size_t)B * 8 * 4;
    float* LIM = (float*)(ws + off);      off += (size_t)B * 4;
    int* C0 = (int*)(ws + off);           off += (size_t)B * 4;
    unsigned* CNTp = (unsigned*)(ws + off); off += (size_t)B * 8 * 4;
    unsigned* CHp = (unsigned*)(ws + off);  off += (size_t)B * 8 * NB * 4;
    float* CS = (float*)(ws + off);       off += (size_t)B * 128 * 4;
    unsigned* LISTV = (unsigned*)(ws + off);
    size_t rem = (ws_size > off) ? (ws_size - off) : 0;
    size_t cap = rem / ((size_t)B * 8 * 4 * 2);
    int cap8 = (cap > 4096) ? 4096 : (int)cap;
    if (cap8 < 512) cap8 = 512;
    unsigned* LISTI = LISTV + (size_t)B * 8 * (size_t)cap8;

    ns_a<<<B * 8, 256, 0, stream>>>(logits, temp, Zp, CHp, V);
    ns_a2<<<B, 128, 0, stream>>>(Zp, CHp, LIM, C0);
    ns_b<<<B * 8, 256, 0, stream>>>(logits, temp, C0, SAp, CS, CNTp, LISTV, LISTI, V, cap8);
    ns_c<<<B, 1024, 0, stream>>>(logits, u, temp, LIM, C0, SAp, CS, CNTp, LISTV, LISTI, out, V, cap8);
}